// Round 4
// baseline (1024.178 us; speedup 1.0000x reference)
//
#include <hip/hip_runtime.h>
#include <cfloat>
#include <cstdint>

#define NV    8192
#define NM    32768
#define KNN   16
#define CIN   32
#define COUT  64
#define CPROV 96
#define NCH   4
#define CHUNK 2048   // NV / NCH
#define MT    4      // grid points per wave in mlp kernel
#define MLP_BLOCK 1024
#define WPB   (MLP_BLOCK/64)

// ---------------------------------------------------------------------------
// Kernel 1: partial KNN — each thread owns one grid point m, scans one chunk
// of vertices staged in LDS, keeps lex-smallest (d2, idx) 16.
// d2 arithmetic replicates the golden's gemm path (BLAS/Eigen/XLA, K=3):
//   q = grid*32 (exact), r = vert*32 (exact)
//   qq = (q0*q0 + q1*q1) + q2*q2 ; rr likewise   (plain mul/add, ascending)
//   dot = fma(q2,r2, fma(q1,r1, q0*r0))          (gemm: ascending k, FMA)
//   d2 = (qq + rr) - 2*dot
// ---------------------------------------------------------------------------
__global__ __launch_bounds__(256) void knn_partial_kernel(
    const float* __restrict__ verts,       // (NV,3)
    const float* __restrict__ grid_verts,  // (NM,3)
    float2* __restrict__ cand)             // (NM, NCH*KNN) as (d2, idx-bits)
{
    __shared__ float4 sv[CHUNK];
    const int tid   = threadIdx.x;
    const int m     = blockIdx.x * 256 + tid;
    const int chunk = blockIdx.y;

    for (int k = 0; k < CHUNK / 256; ++k) {
        int t = k * 256 + tid;
        int v = chunk * CHUNK + t;
        float r0 = __fmul_rn(verts[v * 3 + 0], 32.0f);
        float r1 = __fmul_rn(verts[v * 3 + 1], 32.0f);
        float r2 = __fmul_rn(verts[v * 3 + 2], 32.0f);
        float rr = __fadd_rn(__fadd_rn(__fmul_rn(r0, r0), __fmul_rn(r1, r1)),
                             __fmul_rn(r2, r2));
        sv[t] = make_float4(r0, r1, r2, rr);
    }
    __syncthreads();

    float q0 = __fmul_rn(grid_verts[m * 3 + 0], 32.0f);
    float q1 = __fmul_rn(grid_verts[m * 3 + 1], 32.0f);
    float q2 = __fmul_rn(grid_verts[m * 3 + 2], 32.0f);
    float qq = __fadd_rn(__fadd_rn(__fmul_rn(q0, q0), __fmul_rn(q1, q1)),
                         __fmul_rn(q2, q2));

    float bd[KNN]; int bi[KNN];
#pragma unroll
    for (int s = 0; s < KNN; ++s) { bd[s] = FLT_MAX; bi[s] = 0x7FFFFFFF; }
    float wv = FLT_MAX; int wslot = 0;

    for (int t = 0; t < CHUNK; ++t) {
        float4 v = sv[t];
        // gemm-style dot: ascending k with FMA contraction
        float dot = fmaf(q2, v.z, fmaf(q1, v.y, __fmul_rn(q0, v.x)));
        float d2 = __fsub_rn(__fadd_rn(qq, v.w), __fmul_rn(2.0f, dot));
        // Candidate idx is strictly increasing within a chunk, so lex-insert
        // reduces to strict d2 < worst. Ties at the boundary correctly keep
        // the earlier index (stable top_k semantics).
        if (d2 < wv) {
            int idx = chunk * CHUNK + t;
#pragma unroll
            for (int s = 0; s < KNN; ++s)
                if (s == wslot) { bd[s] = d2; bi[s] = idx; }
            // recompute worst = lex-max (d2, idx)
            wv = bd[0]; int wi = bi[0]; wslot = 0;
#pragma unroll
            for (int s = 1; s < KNN; ++s) {
                bool worse = (bd[s] > wv) || (bd[s] == wv && bi[s] > wi);
                if (worse) { wv = bd[s]; wi = bi[s]; wslot = s; }
            }
        }
    }
    float2* o = cand + (size_t)m * (NCH * KNN) + chunk * KNN;
#pragma unroll
    for (int s = 0; s < KNN; ++s) o[s] = make_float2(bd[s], __int_as_float(bi[s]));
}

// ---------------------------------------------------------------------------
// Kernel 2: merge NCH*16 candidates per m into final 16 (full lex compare —
// within-chunk lists are unsorted by index).
// ---------------------------------------------------------------------------
__global__ __launch_bounds__(256) void knn_merge_kernel(
    const float2* __restrict__ cand, int* __restrict__ knn_idx)
{
    const int m = blockIdx.x * 256 + threadIdx.x;
    float bd[KNN]; int bi[KNN];
#pragma unroll
    for (int s = 0; s < KNN; ++s) { bd[s] = FLT_MAX; bi[s] = 0x7FFFFFFF; }
    float wv = FLT_MAX; int wi = 0x7FFFFFFF; int wslot = 0;

    for (int k = 0; k < NCH * KNN; ++k) {
        float2 cd = cand[(size_t)m * (NCH * KNN) + k];
        float d = cd.x; int i = __float_as_int(cd.y);
        bool ins = (d < wv) || (d == wv && i < wi);
        if (ins) {
#pragma unroll
            for (int s = 0; s < KNN; ++s)
                if (s == wslot) { bd[s] = d; bi[s] = i; }
            wv = bd[0]; wi = bi[0]; wslot = 0;
#pragma unroll
            for (int s = 1; s < KNN; ++s) {
                bool worse = (bd[s] > wv) || (bd[s] == wv && bi[s] > wi);
                if (worse) { wv = bd[s]; wi = bi[s]; wslot = s; }
            }
        }
    }
#pragma unroll
    for (int s = 0; s < KNN; ++s) knn_idx[m * KNN + s] = bi[s];
}

// ---------------------------------------------------------------------------
// Kernel 3: per-vertex precompute  pre[n][c] = feat[n]@ew1[0:32,c] + eb1[c]
// ---------------------------------------------------------------------------
__global__ __launch_bounds__(256) void pre_edge_kernel(
    const float* __restrict__ feats, const float* __restrict__ ew1,
    const float* __restrict__ eb1, float* __restrict__ pre)
{
    int t = blockIdx.x * 256 + threadIdx.x;
    int n = t >> 6, c = t & 63;
    float acc = eb1[c];
#pragma unroll
    for (int i = 0; i < CIN; ++i)
        acc = fmaf(feats[n * CIN + i], ew1[i * COUT + c], acc);
    pre[t] = acc;
}

// ---------------------------------------------------------------------------
// Kernel 4: main MLP. One wave handles MT=4 grid points (lane = channel).
// ---------------------------------------------------------------------------
__device__ inline float gelu_tanh(float x) {
    float x3 = x * x * x;
    float u = 0.7978845608028654f * (x + 0.044715f * x3);
    return 0.5f * x * (1.0f + tanhf(u));
}

__device__ inline float lane_bcast(float v, int lane) {
    return __uint_as_float(__builtin_amdgcn_readlane(__float_as_uint(v), lane));
}

__global__ __launch_bounds__(MLP_BLOCK) void mlp_kernel(
    const float* __restrict__ verts,
    const float* __restrict__ grid_verts,
    const float* __restrict__ grid_feat,
    const float* __restrict__ pre,
    const int*   __restrict__ knn_idx,
    const float* __restrict__ ew1,
    const float* __restrict__ eg1, const float* __restrict__ ebt1,
    const float* __restrict__ ew2, const float* __restrict__ eb2,
    const float* __restrict__ ow1, const float* __restrict__ ob1,
    const float* __restrict__ og1, const float* __restrict__ obt1,
    const float* __restrict__ ow2, const float* __restrict__ ob2,
    float* __restrict__ out)
{
    __shared__ float s_ew1r[3 * 64];      // rel_pos rows of ew1
    __shared__ float s_ew2[64 * 64];
    __shared__ float s_ow1[160 * 64];
    __shared__ float s_ow2[64 * 64];
    __shared__ float s_eg1[64], s_ebt1[64], s_eb2[64];
    __shared__ float s_ob1[64], s_og1[64], s_obt1[64], s_ob2[64];

    const int tid = threadIdx.x;
    for (int t = tid; t < 3 * 64;  t += MLP_BLOCK) s_ew1r[t] = ew1[32 * 64 + t];
    for (int t = tid; t < 64 * 64; t += MLP_BLOCK) s_ew2[t]  = ew2[t];
    for (int t = tid; t < 160 * 64; t += MLP_BLOCK) s_ow1[t] = ow1[t];
    for (int t = tid; t < 64 * 64; t += MLP_BLOCK) s_ow2[t]  = ow2[t];
    if (tid < 64) {
        s_eg1[tid] = eg1[tid];  s_ebt1[tid] = ebt1[tid]; s_eb2[tid] = eb2[tid];
        s_ob1[tid] = ob1[tid];  s_og1[tid] = og1[tid];
        s_obt1[tid] = obt1[tid]; s_ob2[tid] = ob2[tid];
    }
    __syncthreads();

    const int lane = tid & 63;
    const int wave = tid >> 6;
    const int gw   = blockIdx.x * WPB + wave;
    const int c    = lane;
    const int ngroups = NM / MT;
    const int nwaves  = gridDim.x * WPB;

    for (int grp = gw; grp < ngroups; grp += nwaves) {
        const int m0 = __builtin_amdgcn_readfirstlane(grp * MT);

        float agg[MT];
#pragma unroll
        for (int p = 0; p < MT; ++p) agg[p] = 0.0f;

        for (int j = 0; j < KNN; ++j) {
            float h[MT];
#pragma unroll
            for (int p = 0; p < MT; ++p) {
                int n = knn_idx[(m0 + p) * KNN + j];
                float hv = pre[(size_t)n * COUT + c];
#pragma unroll
                for (int d = 0; d < 3; ++d) {
                    float rel = verts[n * 3 + d] - grid_verts[(m0 + p) * 3 + d];
                    hv = fmaf(rel, s_ew1r[d * 64 + c], hv);
                }
                h[p] = hv;
            }
            // LayerNorm (64 channels across the wave) + GELU
#pragma unroll
            for (int p = 0; p < MT; ++p) {
                float x = h[p];
                float s = x, s2 = x * x;
#pragma unroll
                for (int off = 32; off; off >>= 1) {
                    s  += __shfl_xor(s, off);
                    s2 += __shfl_xor(s2, off);
                }
                float mean = s * (1.0f / 64.0f);
                float var  = s2 * (1.0f / 64.0f) - mean * mean;
                float xn = (x - mean) * rsqrtf(var + 1e-5f);
                h[p] = gelu_tanh(xn * s_eg1[c] + s_ebt1[c]);
            }
            // h2 = g @ ew2 + eb2; accumulate into agg
            float acc[MT];
#pragma unroll
            for (int p = 0; p < MT; ++p) acc[p] = s_eb2[c];
            for (int jj = 0; jj < 64; ++jj) {
                float w = s_ew2[jj * 64 + c];
#pragma unroll
                for (int p = 0; p < MT; ++p)
                    acc[p] = fmaf(lane_bcast(h[p], jj), w, acc[p]);
            }
#pragma unroll
            for (int p = 0; p < MT; ++p) agg[p] += acc[p];
        }
#pragma unroll
        for (int p = 0; p < MT; ++p) agg[p] *= (1.0f / 16.0f);

        // ---- out MLP: o = [agg(64), grid_feat(96)] @ ow1 + ob1 ----
        float t1[MT];
#pragma unroll
        for (int p = 0; p < MT; ++p) t1[p] = s_ob1[c];
        for (int jj = 0; jj < 64; ++jj) {
            float w = s_ow1[jj * 64 + c];
#pragma unroll
            for (int p = 0; p < MT; ++p)
                t1[p] = fmaf(lane_bcast(agg[p], jj), w, t1[p]);
        }
        for (int i = 0; i < CPROV; ++i) {
            float w = s_ow1[(64 + i) * 64 + c];
#pragma unroll
            for (int p = 0; p < MT; ++p) {
                float gf = grid_feat[(size_t)(m0 + p) * CPROV + i];
                t1[p] = fmaf(gf, w, t1[p]);
            }
        }
#pragma unroll
        for (int p = 0; p < MT; ++p) {
            float x = t1[p];
            float s = x, s2 = x * x;
#pragma unroll
            for (int off = 32; off; off >>= 1) {
                s  += __shfl_xor(s, off);
                s2 += __shfl_xor(s2, off);
            }
            float mean = s * (1.0f / 64.0f);
            float var  = s2 * (1.0f / 64.0f) - mean * mean;
            float xn = (x - mean) * rsqrtf(var + 1e-5f);
            t1[p] = gelu_tanh(xn * s_og1[c] + s_obt1[c]);
        }
        float o[MT];
#pragma unroll
        for (int p = 0; p < MT; ++p) o[p] = s_ob2[c];
        for (int jj = 0; jj < 64; ++jj) {
            float w = s_ow2[jj * 64 + c];
#pragma unroll
            for (int p = 0; p < MT; ++p)
                o[p] = fmaf(lane_bcast(t1[p], jj), w, o[p]);
        }
#pragma unroll
        for (int p = 0; p < MT; ++p)
            out[(size_t)(m0 + p) * COUT + c] = o[p];
    }
}

// ---------------------------------------------------------------------------
extern "C" void kernel_launch(void* const* d_in, const int* in_sizes, int n_in,
                              void* d_out, int out_size, void* d_ws, size_t ws_size,
                              hipStream_t stream)
{
    const float* verts  = (const float*)d_in[0];
    const float* feats  = (const float*)d_in[1];
    const float* gverts = (const float*)d_in[2];
    const float* gfeat  = (const float*)d_in[3];
    const float* ew1    = (const float*)d_in[4];
    const float* eb1    = (const float*)d_in[5];
    const float* eg1    = (const float*)d_in[6];
    const float* ebt1   = (const float*)d_in[7];
    const float* ew2    = (const float*)d_in[8];
    const float* eb2    = (const float*)d_in[9];
    const float* ow1    = (const float*)d_in[10];
    const float* ob1    = (const float*)d_in[11];
    const float* og1    = (const float*)d_in[12];
    const float* obt1   = (const float*)d_in[13];
    const float* ow2    = (const float*)d_in[14];
    const float* ob2    = (const float*)d_in[15];
    float* out = (float*)d_out;

    char* ws = (char*)d_ws;
    float2* cand  = (float2*)ws;                                   // 16.78 MB
    int* knn_idx  = (int*)(ws + (size_t)NM * NCH * KNN * 8);       // 2 MB
    float* pre    = (float*)(ws + (size_t)NM * NCH * KNN * 8
                                + (size_t)NM * KNN * 4);           // 2 MB

    knn_partial_kernel<<<dim3(NM / 256, NCH), 256, 0, stream>>>(verts, gverts, cand);
    knn_merge_kernel<<<NM / 256, 256, 0, stream>>>(cand, knn_idx);
    pre_edge_kernel<<<(NV * COUT) / 256, 256, 0, stream>>>(feats, ew1, eb1, pre);
    mlp_kernel<<<256, MLP_BLOCK, 0, stream>>>(verts, gverts, gfeat, pre, knn_idx,
        ew1, eg1, ebt1, ew2, eb2, ow1, ob1, og1, obt1, ow2, ob2, out);
}

// Round 6
// 608.659 us; speedup vs baseline: 1.6827x; 1.6827x over previous
//
#include <hip/hip_runtime.h>
#include <cfloat>
#include <cstdint>

#define NV    8192
#define NM    32768
#define KNN   16
#define CIN   32
#define COUT  64
#define CPROV 96
#define NCH   4
#define CHUNK 2048   // NV / NCH
#define MT    8      // grid points per wave in mlp kernel
#define MLP_BLOCK 1024
#define WPB   (MLP_BLOCK/64)

// ===========================================================================
// KNN: R4's PROVEN bit-exact brute-force selection (golden d2 path:
//   qq/rr plain ascending mul/add; dot = ascending-k FMA chain;
//   d2 = (qq+rr) - 2*dot; strict < insert in index order)
// accelerated by a CERTIFIED gate: bins give tau[m] = 3*(R+1)^2 where the
// radius-R cell cube holds >= 16 points  =>  16th-NN d2 <= tau. Points with
// d2 > tau + 0.12 cannot be in the top-16; gate slack 0.125 >> fp-path noise
// (~2e-3), so every golden-kept point reaches the exact insert. Selection is
// therefore IDENTICAL to R4's.
// ===========================================================================

__device__ __forceinline__ int bin_of(float x) {
    int b = (int)(x * 32.0f);
    return min(31, max(0, b));
}

__global__ __launch_bounds__(256) void bin_count_kernel(
    const float* __restrict__ verts, int* __restrict__ counts)
{
    int v = blockIdx.x * 256 + threadIdx.x;
    int bx = bin_of(verts[v * 3 + 0]);
    int by = bin_of(verts[v * 3 + 1]);
    int bz = bin_of(verts[v * 3 + 2]);
    atomicAdd(&counts[(bx * 32 + by) * 32 + bz], 1);
}

__global__ __launch_bounds__(1024) void prefix_kernel(
    const int* __restrict__ counts, int* __restrict__ prefix)
{
    __shared__ int lds[1024];
    int tid = threadIdx.x;
    int local[32]; int s = 0;
#pragma unroll
    for (int i = 0; i < 32; ++i) { local[i] = counts[tid * 32 + i]; s += local[i]; }
    lds[tid] = s; __syncthreads();
    for (int off = 1; off < 1024; off <<= 1) {
        int v = (tid >= off) ? lds[tid - off] : 0;
        __syncthreads();
        lds[tid] += v;
        __syncthreads();
    }
    int run = lds[tid] - s;
#pragma unroll
    for (int i = 0; i < 32; ++i) { prefix[tid * 32 + i] = run; run += local[i]; }
    if (tid == 1023) prefix[32768] = run;
}

// per-query certified upper bound tau on the 16th-NN squared distance
__global__ __launch_bounds__(256) void radius_kernel(
    const float* __restrict__ grid_verts, const int* __restrict__ prefix,
    float* __restrict__ tau)
{
    int m = blockIdx.x * 256 + threadIdx.x;
    int bx = bin_of(grid_verts[m * 3 + 0]);
    int by = bin_of(grid_verts[m * 3 + 1]);
    int bz = bin_of(grid_verts[m * 3 + 2]);
    int R = 1;
    for (; R < 32; ++R) {
        int cnt = 0;
        int xlo = max(0, bx - R), xhi = min(31, bx + R);
        int ylo = max(0, by - R), yhi = min(31, by + R);
        int zlo = max(0, bz - R), zhi = min(31, bz + R);
        for (int x = xlo; x <= xhi; ++x)
            for (int y = ylo; y <= yhi; ++y) {
                int c = (x * 32 + y) * 32;
                cnt += prefix[c + zhi + 1] - prefix[c + zlo];
            }
        if (cnt >= KNN) break;
    }
    float Rp = (float)(R + 1);
    tau[m] = 3.0f * Rp * Rp;
}

__global__ __launch_bounds__(256) void knn_partial_kernel(
    const float* __restrict__ verts,
    const float* __restrict__ grid_verts,
    const float* __restrict__ tau,
    float2* __restrict__ cand)
{
    __shared__ float4 sv[CHUNK];
    const int tid   = threadIdx.x;
    const int m     = blockIdx.x * 256 + tid;
    const int chunk = blockIdx.y;

    for (int k = 0; k < CHUNK / 256; ++k) {
        int t = k * 256 + tid;
        int v = chunk * CHUNK + t;
        float r0 = __fmul_rn(verts[v * 3 + 0], 32.0f);
        float r1 = __fmul_rn(verts[v * 3 + 1], 32.0f);
        float r2 = __fmul_rn(verts[v * 3 + 2], 32.0f);
        float rr = __fadd_rn(__fadd_rn(__fmul_rn(r0, r0), __fmul_rn(r1, r1)),
                             __fmul_rn(r2, r2));
        sv[t] = make_float4(r0, r1, r2, rr);
    }
    __syncthreads();

    float q0 = __fmul_rn(grid_verts[m * 3 + 0], 32.0f);
    float q1 = __fmul_rn(grid_verts[m * 3 + 1], 32.0f);
    float q2 = __fmul_rn(grid_verts[m * 3 + 2], 32.0f);
    float qq = __fadd_rn(__fadd_rn(__fmul_rn(q0, q0), __fmul_rn(q1, q1)),
                         __fmul_rn(q2, q2));
    // conservative gate threshold in the (rr - 2dot) domain
    float gthr = (tau[m] - qq) + 0.125f;

    float bd[KNN]; int bi[KNN];
#pragma unroll
    for (int s = 0; s < KNN; ++s) { bd[s] = FLT_MAX; bi[s] = 0x7FFFFFFF; }
    float wv = FLT_MAX; int wslot = 0;

    for (int t = 0; t < CHUNK; ++t) {
        float4 v = sv[t];
        float dot = fmaf(q2, v.z, fmaf(q1, v.y, __fmul_rn(q0, v.x)));
        float val = fmaf(-2.0f, dot, v.w);
        if (val < gthr) {
            // exact golden d2 path + R4's exact insert
            float d2 = __fsub_rn(__fadd_rn(qq, v.w), __fmul_rn(2.0f, dot));
            if (d2 < wv) {
                int idx = chunk * CHUNK + t;
#pragma unroll
                for (int s = 0; s < KNN; ++s)
                    if (s == wslot) { bd[s] = d2; bi[s] = idx; }
                wv = bd[0]; int wi = bi[0]; wslot = 0;
#pragma unroll
                for (int s = 1; s < KNN; ++s) {
                    bool worse = (bd[s] > wv) || (bd[s] == wv && bi[s] > wi);
                    if (worse) { wv = bd[s]; wi = bi[s]; wslot = s; }
                }
            }
        }
    }
    float2* o = cand + (size_t)m * (NCH * KNN) + chunk * KNN;
#pragma unroll
    for (int s = 0; s < KNN; ++s) o[s] = make_float2(bd[s], __int_as_float(bi[s]));
}

__global__ __launch_bounds__(256) void knn_merge_kernel(
    const float2* __restrict__ cand, int* __restrict__ knn_idx)
{
    const int m = blockIdx.x * 256 + threadIdx.x;
    float bd[KNN]; int bi[KNN];
#pragma unroll
    for (int s = 0; s < KNN; ++s) { bd[s] = FLT_MAX; bi[s] = 0x7FFFFFFF; }
    float wv = FLT_MAX; int wi = 0x7FFFFFFF; int wslot = 0;

    for (int k = 0; k < NCH * KNN; ++k) {
        float2 cd = cand[(size_t)m * (NCH * KNN) + k];
        float d = cd.x; int i = __float_as_int(cd.y);
        bool ins = (d < wv) || (d == wv && i < wi);
        if (ins) {
#pragma unroll
            for (int s = 0; s < KNN; ++s)
                if (s == wslot) { bd[s] = d; bi[s] = i; }
            wv = bd[0]; wi = bi[0]; wslot = 0;
#pragma unroll
            for (int s = 1; s < KNN; ++s) {
                bool worse = (bd[s] > wv) || (bd[s] == wv && bi[s] > wi);
                if (worse) { wv = bd[s]; wi = bi[s]; wslot = s; }
            }
        }
    }
#pragma unroll
    for (int s = 0; s < KNN; ++s) knn_idx[m * KNN + s] = bi[s];
}

// ===========================================================================
// MLP precompute
// ===========================================================================

// 9 global constants from ew1 rel-pos rows: W1s[d] = sum_c w_dc,
// G[de] = sum_c w_dc*w_ec (order: Gxx,Gyy,Gzz,Gxy,Gxz,Gyz)
__global__ void const_kernel(const float* __restrict__ ew1, float* __restrict__ cst)
{
    int c = threadIdx.x;   // 64 threads
    float w0 = ew1[32 * 64 + c], w1 = ew1[33 * 64 + c], w2 = ew1[34 * 64 + c];
    float v[9] = { w0, w1, w2, w0*w0, w1*w1, w2*w2, w0*w1, w0*w2, w1*w2 };
#pragma unroll
    for (int k = 0; k < 9; ++k) {
#pragma unroll
        for (int off = 32; off; off >>= 1) v[k] += __shfl_xor(v[k], off);
    }
    if (c == 0) {
        cst[0] = v[0]; cst[1] = v[1]; cst[2] = v[2];
        cst[3] = v[3]; cst[4] = v[4]; cst[5] = v[5];
        cst[6] = v[6]; cst[7] = v[7]; cst[8] = v[8];
    }
}

// pre[n][c] = feat[n]@ew1[0:32,c] + eb1[c]; aux[n] = {S1, Q, P1x, P1y, P1z}
// (row sum, row sum-of-squares, row dot with each rel-pos weight row)
__global__ __launch_bounds__(256) void pre_edge_kernel(
    const float* __restrict__ feats, const float* __restrict__ ew1,
    const float* __restrict__ eb1, float* __restrict__ pre,
    float* __restrict__ aux)
{
    int t = blockIdx.x * 256 + threadIdx.x;
    int n = t >> 6, c = t & 63;
    float acc = eb1[c];
#pragma unroll
    for (int i = 0; i < CIN; ++i)
        acc = fmaf(feats[n * CIN + i], ew1[i * COUT + c], acc);
    pre[t] = acc;

    float w0 = ew1[32 * 64 + c], w1 = ew1[33 * 64 + c], w2 = ew1[34 * 64 + c];
    float v[5] = { acc, acc * acc, acc * w0, acc * w1, acc * w2 };
#pragma unroll
    for (int k = 0; k < 5; ++k) {
#pragma unroll
        for (int off = 32; off; off >>= 1) v[k] += __shfl_xor(v[k], off);
    }
    if (c == 0) {
        aux[n * 8 + 0] = v[0]; aux[n * 8 + 1] = v[1];
        aux[n * 8 + 2] = v[2]; aux[n * 8 + 3] = v[3]; aux[n * 8 + 4] = v[4];
    }
}

// ===========================================================================
// Main MLP. One wave = MT=8 grid points, lane = channel.
// agg = mean_j gelu(LN(h_j)) @ ew2 + eb2   (mean commuted past linear layer)
// LN1 stats closed-form from aux/cst (no shuffles in j-loop).
// ===========================================================================
__device__ __forceinline__ float gelu_fast(float x) {
    float t = fmaf(0.044715f, x * x, 1.0f);
    float u = 0.7978845608028654f * x * t;          // sqrt(2/pi)(x+0.044715x^3)
    float e = __expf(-2.0f * u);
    return x * __builtin_amdgcn_rcpf(1.0f + e);     // x * sigmoid(2u)
}

__device__ __forceinline__ float lane_bcast(float v, int lane) {
    return __uint_as_float(__builtin_amdgcn_readlane(__float_as_uint(v), lane));
}

__global__ __launch_bounds__(MLP_BLOCK) void mlp_kernel(
    const float* __restrict__ verts,
    const float* __restrict__ grid_verts,
    const float* __restrict__ grid_feat,
    const float* __restrict__ pre,
    const float* __restrict__ aux,
    const float* __restrict__ cst,
    const int*   __restrict__ knn_idx,
    const float* __restrict__ ew1,
    const float* __restrict__ eg1, const float* __restrict__ ebt1,
    const float* __restrict__ ew2, const float* __restrict__ eb2,
    const float* __restrict__ ow1, const float* __restrict__ ob1,
    const float* __restrict__ og1, const float* __restrict__ obt1,
    const float* __restrict__ ow2, const float* __restrict__ ob2,
    float* __restrict__ out)
{
    __shared__ float s_ew1r[3 * 64];
    __shared__ float s_ew2[64 * 64];
    __shared__ float s_ow1[160 * 64];
    __shared__ float s_ow2[64 * 64];
    __shared__ float s_eg1[64], s_ebt1[64], s_eb2[64];
    __shared__ float s_ob1[64], s_og1[64], s_obt1[64], s_ob2[64];

    const int tid = threadIdx.x;
    for (int t = tid; t < 3 * 64;  t += MLP_BLOCK) s_ew1r[t] = ew1[32 * 64 + t];
    for (int t = tid; t < 64 * 64; t += MLP_BLOCK) s_ew2[t]  = ew2[t];
    for (int t = tid; t < 160 * 64; t += MLP_BLOCK) s_ow1[t] = ow1[t];
    for (int t = tid; t < 64 * 64; t += MLP_BLOCK) s_ow2[t]  = ow2[t];
    if (tid < 64) {
        s_eg1[tid] = eg1[tid];  s_ebt1[tid] = ebt1[tid]; s_eb2[tid] = eb2[tid];
        s_ob1[tid] = ob1[tid];  s_og1[tid] = og1[tid];
        s_obt1[tid] = obt1[tid]; s_ob2[tid] = ob2[tid];
    }
    __syncthreads();

    const int lane = tid & 63;
    const int wave = tid >> 6;
    const int c    = lane;
    const int grp  = blockIdx.x * WPB + wave;     // 4096 groups exactly
    const int m0   = __builtin_amdgcn_readfirstlane(grp * MT);

    // LN1 closed-form constants
    const float Ws0 = cst[0], Ws1 = cst[1], Ws2 = cst[2];
    const float Gxx = cst[3], Gyy = cst[4], Gzz = cst[5];
    const float Gxy = cst[6], Gxz = cst[7], Gyz = cst[8];

    float gvx[MT], gvy[MT], gvz[MT];
#pragma unroll
    for (int p = 0; p < MT; ++p) {
        gvx[p] = grid_verts[(m0 + p) * 3 + 0];
        gvy[p] = grid_verts[(m0 + p) * 3 + 1];
        gvz[p] = grid_verts[(m0 + p) * 3 + 2];
    }

    float gsum[MT];
#pragma unroll
    for (int p = 0; p < MT; ++p) gsum[p] = 0.0f;

    const float inv64 = 1.0f / 64.0f;
    for (int p = 0; p < MT; ++p) {
        for (int j = 0; j < KNN; ++j) {
            int n = __builtin_amdgcn_readfirstlane(knn_idx[(m0 + p) * KNN + j]);
            float S1  = aux[n * 8 + 0], Q = aux[n * 8 + 1];
            float P1x = aux[n * 8 + 2], P1y = aux[n * 8 + 3], P1z = aux[n * 8 + 4];
            float rx = verts[n * 3 + 0] - gvx[p];
            float ry = verts[n * 3 + 1] - gvy[p];
            float rz = verts[n * 3 + 2] - gvz[p];
            // per-channel pre-activation
            float hv = pre[(size_t)n * COUT + c];
            hv = fmaf(rx, s_ew1r[0 * 64 + c], hv);
            hv = fmaf(ry, s_ew1r[1 * 64 + c], hv);
            hv = fmaf(rz, s_ew1r[2 * 64 + c], hv);
            // closed-form channel statistics
            float s1 = S1 + rx * Ws0 + ry * Ws1 + rz * Ws2;
            float s2 = Q + 2.0f * (rx * P1x + ry * P1y + rz * P1z)
                     + rx * rx * Gxx + ry * ry * Gyy + rz * rz * Gzz
                     + 2.0f * (rx * ry * Gxy + rx * rz * Gxz + ry * rz * Gyz);
            float mean = s1 * inv64;
            float var  = s2 * inv64 - mean * mean;
            float xn = (hv - mean) * rsqrtf(var + 1e-5f);
            gsum[p] += gelu_fast(xn * s_eg1[c] + s_ebt1[c]);
        }
    }

    // agg = (gsum/16) @ ew2 + eb2
    float A[MT];
#pragma unroll
    for (int p = 0; p < MT; ++p) { gsum[p] *= (1.0f / 16.0f); A[p] = s_eb2[c]; }
    for (int jj = 0; jj < 64; ++jj) {
        float w = s_ew2[jj * 64 + c];
#pragma unroll
        for (int p = 0; p < MT; ++p)
            A[p] = fmaf(lane_bcast(gsum[p], jj), w, A[p]);
    }

    // t1 = [A, grid_feat] @ ow1 + ob1
    float gfa[MT], gfb[MT];
#pragma unroll
    for (int p = 0; p < MT; ++p) {
        gfa[p] = grid_feat[(size_t)(m0 + p) * CPROV + c];
        gfb[p] = grid_feat[(size_t)(m0 + p) * CPROV + 64 + (c & 31)];
    }
    float t1[MT];
#pragma unroll
    for (int p = 0; p < MT; ++p) t1[p] = s_ob1[c];
    for (int jj = 0; jj < 64; ++jj) {
        float w = s_ow1[jj * 64 + c];
#pragma unroll
        for (int p = 0; p < MT; ++p)
            t1[p] = fmaf(lane_bcast(A[p], jj), w, t1[p]);
    }
    for (int i = 0; i < 64; ++i) {
        float w = s_ow1[(64 + i) * 64 + c];
#pragma unroll
        for (int p = 0; p < MT; ++p)
            t1[p] = fmaf(lane_bcast(gfa[p], i), w, t1[p]);
    }
    for (int i = 0; i < 32; ++i) {
        float w = s_ow1[(128 + i) * 64 + c];
#pragma unroll
        for (int p = 0; p < MT; ++p)
            t1[p] = fmaf(lane_bcast(gfb[p], i), w, t1[p]);
    }

    // LN2 + gelu
#pragma unroll
    for (int p = 0; p < MT; ++p) {
        float x = t1[p];
        float s = x, s2 = x * x;
#pragma unroll
        for (int off = 32; off; off >>= 1) {
            s  += __shfl_xor(s, off);
            s2 += __shfl_xor(s2, off);
        }
        float mean = s * inv64;
        float var  = s2 * inv64 - mean * mean;
        float xn = (x - mean) * rsqrtf(var + 1e-5f);
        t1[p] = gelu_fast(xn * s_og1[c] + s_obt1[c]);
    }

    // out = t1 @ ow2 + ob2
    float o[MT];
#pragma unroll
    for (int p = 0; p < MT; ++p) o[p] = s_ob2[c];
    for (int jj = 0; jj < 64; ++jj) {
        float w = s_ow2[jj * 64 + c];
#pragma unroll
        for (int p = 0; p < MT; ++p)
            o[p] = fmaf(lane_bcast(t1[p], jj), w, o[p]);
    }
#pragma unroll
    for (int p = 0; p < MT; ++p)
        out[(size_t)(m0 + p) * COUT + c] = o[p];
}

// ---------------------------------------------------------------------------
extern "C" void kernel_launch(void* const* d_in, const int* in_sizes, int n_in,
                              void* d_out, int out_size, void* d_ws, size_t ws_size,
                              hipStream_t stream)
{
    const float* verts  = (const float*)d_in[0];
    const float* feats  = (const float*)d_in[1];
    const float* gverts = (const float*)d_in[2];
    const float* gfeat  = (const float*)d_in[3];
    const float* ew1    = (const float*)d_in[4];
    const float* eb1    = (const float*)d_in[5];
    const float* eg1    = (const float*)d_in[6];
    const float* ebt1   = (const float*)d_in[7];
    const float* ew2    = (const float*)d_in[8];
    const float* eb2    = (const float*)d_in[9];
    const float* ow1    = (const float*)d_in[10];
    const float* ob1    = (const float*)d_in[11];
    const float* og1    = (const float*)d_in[12];
    const float* obt1   = (const float*)d_in[13];
    const float* ow2    = (const float*)d_in[14];
    const float* ob2    = (const float*)d_in[15];
    float* out = (float*)d_out;

    char* ws = (char*)d_ws;
    // cand (16.78 MB) is dead after knn_merge; pre/aux/cst overlay it.
    float2* cand    = (float2*)ws;                        // [0, 16777216)
    float*  pre     = (float*)ws;                         // overlay after merge
    float*  aux     = (float*)(ws + 2097152);
    float*  cst     = (float*)(ws + 2359296);
    int*    knn_idx = (int*)(ws + 16777216);              // 2 MB
    int*    counts  = (int*)(ws + 18874368);              // 128 KB
    int*    prefix  = (int*)(ws + 19005440);              // 32769 ints
    float*  tau     = (float*)(ws + 19136528);            // 128 KB

    hipMemsetAsync(counts, 0, 32768 * sizeof(int), stream);
    bin_count_kernel<<<NV / 256, 256, 0, stream>>>(verts, counts);
    prefix_kernel<<<1, 1024, 0, stream>>>(counts, prefix);
    radius_kernel<<<NM / 256, 256, 0, stream>>>(gverts, prefix, tau);
    knn_partial_kernel<<<dim3(NM / 256, NCH), 256, 0, stream>>>(verts, gverts, tau, cand);
    knn_merge_kernel<<<NM / 256, 256, 0, stream>>>(cand, knn_idx);
    // cand dead from here; pre/aux/cst reuse its space
    pre_edge_kernel<<<(NV * COUT) / 256, 256, 0, stream>>>(feats, ew1, eb1, pre, aux);
    const_kernel<<<1, 64, 0, stream>>>(ew1, cst);
    mlp_kernel<<<NM / (MT * WPB), MLP_BLOCK, 0, stream>>>(verts, gverts, gfeat,
        pre, aux, cst, knn_idx,
        ew1, eg1, ebt1, ew2, eb2, ow1, ob1, og1, obt1, ow2, ob2, out);
}

// Round 8
// 494.554 us; speedup vs baseline: 2.0709x; 1.2307x over previous
//
#include <hip/hip_runtime.h>
#include <cfloat>
#include <cstdint>

#define NV    8192
#define NM    32768
#define KNN   16
#define CIN   32
#define COUT  64
#define CPROV 96
#define NCH   4
#define CHUNK 2048   // NV / NCH
#define SUB   256
#define NSUB  (CHUNK / SUB)
#define CAP   32
#define MT    8      // grid points per wave in mlp kernel
#define MLP_BLOCK 1024
#define WPB   (MLP_BLOCK/64)

// ===========================================================================
// KNN: R6's validated structure (full scan, index order, tau-gate), made fast.
// Selection = min-16 of u64 keys, key = (ord(d2)<<32)|idx where ord() is the
// order-preserving float->u32 map. Golden d2 path (validated R4/R6):
//   q=grid*32, r=vert*32 (exact); qq/rr plain ascending mul/add;
//   dot = fma(q2,r2, fma(q1,r1, q0*r0)); d2 = (qq+rr)-2*dot.
// Gate: a[] seeded with key(tau+0.13) (R6-validated margin), condition
// key < a[15] self-tightens; passers buffered in private LDS FIFO; merged
// via branchless sorted insert per 256-candidate sub-chunk.
// ===========================================================================

__device__ __forceinline__ unsigned long long d2key(float d2, unsigned int idx) {
    unsigned int b = __float_as_uint(d2);
    b ^= (b & 0x80000000u) ? 0xFFFFFFFFu : 0x80000000u;  // total-order map
    return ((unsigned long long)b << 32) | idx;
}

__device__ __forceinline__ void key_insert(unsigned long long* a,
                                           unsigned long long key) {
    // branchless sorted (ascending) insert-and-drop-max
#pragma unroll
    for (int i = KNN - 1; i >= 1; --i) {
        unsigned long long hi = (a[i-1] > key) ? a[i-1] : key;
        a[i] = (hi < a[i]) ? hi : a[i];
    }
    a[0] = (key < a[0]) ? key : a[0];
}

__device__ __forceinline__ int bin_of(float x) {
    int b = (int)(x * 32.0f);
    return min(31, max(0, b));
}

__global__ __launch_bounds__(256) void bin_count_kernel(
    const float* __restrict__ verts, int* __restrict__ counts)
{
    int v = blockIdx.x * 256 + threadIdx.x;
    int bx = bin_of(verts[v * 3 + 0]);
    int by = bin_of(verts[v * 3 + 1]);
    int bz = bin_of(verts[v * 3 + 2]);
    atomicAdd(&counts[(bx * 32 + by) * 32 + bz], 1);
}

__global__ __launch_bounds__(1024) void prefix_kernel(
    const int* __restrict__ counts, int* __restrict__ prefix)
{
    __shared__ int lds[1024];
    int tid = threadIdx.x;
    int local[32]; int s = 0;
#pragma unroll
    for (int i = 0; i < 32; ++i) { local[i] = counts[tid * 32 + i]; s += local[i]; }
    lds[tid] = s; __syncthreads();
    for (int off = 1; off < 1024; off <<= 1) {
        int v = (tid >= off) ? lds[tid - off] : 0;
        __syncthreads();
        lds[tid] += v;
        __syncthreads();
    }
    int run = lds[tid] - s;
#pragma unroll
    for (int i = 0; i < 32; ++i) { prefix[tid * 32 + i] = run; run += local[i]; }
    if (tid == 1023) prefix[32768] = run;
}

// tau[m] = 3*(R+1)^2 where radius-R cell cube holds >= 16 points (validated R6)
__global__ __launch_bounds__(256) void radius_kernel(
    const float* __restrict__ grid_verts, const int* __restrict__ prefix,
    float* __restrict__ tau)
{
    int m = blockIdx.x * 256 + threadIdx.x;
    int bx = bin_of(grid_verts[m * 3 + 0]);
    int by = bin_of(grid_verts[m * 3 + 1]);
    int bz = bin_of(grid_verts[m * 3 + 2]);
    int R = 1;
    for (; R < 32; ++R) {
        int cnt = 0;
        int xlo = max(0, bx - R), xhi = min(31, bx + R);
        int ylo = max(0, by - R), yhi = min(31, by + R);
        int zlo = max(0, bz - R), zhi = min(31, bz + R);
        for (int x = xlo; x <= xhi; ++x)
            for (int y = ylo; y <= yhi; ++y) {
                int c = (x * 32 + y) * 32;
                cnt += prefix[c + zhi + 1] - prefix[c + zlo];
            }
        if (cnt >= KNN) break;
    }
    float Rp = (float)(R + 1);
    tau[m] = 3.0f * Rp * Rp;
}

__global__ __launch_bounds__(256, 2) void knn_partial_kernel(
    const float* __restrict__ verts,
    const float* __restrict__ grid_verts,
    const float* __restrict__ tau,
    unsigned long long* __restrict__ cand)   // (NM, NCH*KNN)
{
    __shared__ float4 sv[SUB];
    __shared__ unsigned long long sbuf[CAP][256];
    const int tid   = threadIdx.x;
    const int m     = blockIdx.x * 256 + tid;
    const int chunk = blockIdx.y;

    const float q0 = __fmul_rn(grid_verts[m * 3 + 0], 32.0f);
    const float q1 = __fmul_rn(grid_verts[m * 3 + 1], 32.0f);
    const float q2 = __fmul_rn(grid_verts[m * 3 + 2], 32.0f);
    const float qq = __fadd_rn(__fadd_rn(__fmul_rn(q0, q0), __fmul_rn(q1, q1)),
                               __fmul_rn(q2, q2));

    // seed = key(bound) with idx 0; bound > all golden d2 (R6-validated margin)
    const float bound = tau[m] + 0.13f;
    unsigned int bb = __float_as_uint(bound) ^ 0x80000000u;  // bound > 0
    const unsigned long long seed = ((unsigned long long)bb << 32);

    unsigned long long a[KNN];
#pragma unroll
    for (int s = 0; s < KNN; ++s) a[s] = seed;
    unsigned long long a15 = seed;
    int cnt = 0;

    for (int sub = 0; sub < NSUB; ++sub) {
        __syncthreads();
        {
            int v = chunk * CHUNK + sub * SUB + tid;
            float r0 = __fmul_rn(verts[v * 3 + 0], 32.0f);
            float r1 = __fmul_rn(verts[v * 3 + 1], 32.0f);
            float r2 = __fmul_rn(verts[v * 3 + 2], 32.0f);
            float rr = __fadd_rn(__fadd_rn(__fmul_rn(r0, r0), __fmul_rn(r1, r1)),
                                 __fmul_rn(r2, r2));
            sv[tid] = make_float4(r0, r1, r2, rr);
        }
        __syncthreads();

        const unsigned int base = chunk * CHUNK + sub * SUB;
        for (int t = 0; t < SUB; ++t) {
            float4 v = sv[t];
            float dot = fmaf(q2, v.z, fmaf(q1, v.y, __fmul_rn(q0, v.x)));
            float d2 = __fsub_rn(__fadd_rn(qq, v.w), __fmul_rn(2.0f, dot));
            unsigned long long key = d2key(d2, base + t);
            if (key < a15) {
                if (cnt < CAP) { sbuf[cnt][tid] = key; ++cnt; }
                else { key_insert(a, key); a15 = a[KNN - 1]; }  // rare fallback
            }
        }
        // merge private FIFO (lane-private: no barrier needed)
        int mx = cnt;
#pragma unroll
        for (int off = 32; off; off >>= 1) mx = max(mx, __shfl_xor(mx, off));
        for (int k = 0; k < mx; ++k) {
            unsigned long long key = (k < cnt) ? sbuf[k][tid] : ~0ULL;
            key_insert(a, key);
        }
        a15 = a[KNN - 1];
        cnt = 0;
    }

    unsigned long long* o = cand + (size_t)m * (NCH * KNN) + chunk * KNN;
#pragma unroll
    for (int s = 0; s < KNN; ++s) o[s] = a[s];
}

__global__ __launch_bounds__(256) void knn_merge_kernel(
    const unsigned long long* __restrict__ cand, int* __restrict__ knn_idx)
{
    const int m = blockIdx.x * 256 + threadIdx.x;
    unsigned long long a[KNN];
#pragma unroll
    for (int s = 0; s < KNN; ++s) a[s] = ~0ULL;
    for (int k = 0; k < NCH * KNN; ++k) {
        unsigned long long key = cand[(size_t)m * (NCH * KNN) + k];
        if (key < a[KNN - 1]) key_insert(a, key);
    }
#pragma unroll
    for (int s = 0; s < KNN; ++s)
        knn_idx[m * KNN + s] = (int)(a[s] & 0xFFFFFFFFu);
}

// ===========================================================================
// MLP precompute (unchanged from R6 — passed)
// ===========================================================================

__global__ void const_kernel(const float* __restrict__ ew1, float* __restrict__ cst)
{
    int c = threadIdx.x;   // 64 threads
    float w0 = ew1[32 * 64 + c], w1 = ew1[33 * 64 + c], w2 = ew1[34 * 64 + c];
    float v[9] = { w0, w1, w2, w0*w0, w1*w1, w2*w2, w0*w1, w0*w2, w1*w2 };
#pragma unroll
    for (int k = 0; k < 9; ++k) {
#pragma unroll
        for (int off = 32; off; off >>= 1) v[k] += __shfl_xor(v[k], off);
    }
    if (c == 0) {
        cst[0] = v[0]; cst[1] = v[1]; cst[2] = v[2];
        cst[3] = v[3]; cst[4] = v[4]; cst[5] = v[5];
        cst[6] = v[6]; cst[7] = v[7]; cst[8] = v[8];
    }
}

__global__ __launch_bounds__(256) void pre_edge_kernel(
    const float* __restrict__ feats, const float* __restrict__ ew1,
    const float* __restrict__ eb1, float* __restrict__ pre,
    float* __restrict__ aux)
{
    int t = blockIdx.x * 256 + threadIdx.x;
    int n = t >> 6, c = t & 63;
    float acc = eb1[c];
#pragma unroll
    for (int i = 0; i < CIN; ++i)
        acc = fmaf(feats[n * CIN + i], ew1[i * COUT + c], acc);
    pre[t] = acc;

    float w0 = ew1[32 * 64 + c], w1 = ew1[33 * 64 + c], w2 = ew1[34 * 64 + c];
    float v[5] = { acc, acc * acc, acc * w0, acc * w1, acc * w2 };
#pragma unroll
    for (int k = 0; k < 5; ++k) {
#pragma unroll
        for (int off = 32; off; off >>= 1) v[k] += __shfl_xor(v[k], off);
    }
    if (c == 0) {
        aux[n * 8 + 0] = v[0]; aux[n * 8 + 1] = v[1];
        aux[n * 8 + 2] = v[2]; aux[n * 8 + 3] = v[3]; aux[n * 8 + 4] = v[4];
    }
}

// ===========================================================================
// Main MLP (unchanged from R6 — passed)
// ===========================================================================
__device__ __forceinline__ float gelu_fast(float x) {
    float t = fmaf(0.044715f, x * x, 1.0f);
    float u = 0.7978845608028654f * x * t;
    float e = __expf(-2.0f * u);
    return x * __builtin_amdgcn_rcpf(1.0f + e);
}

__device__ __forceinline__ float lane_bcast(float v, int lane) {
    return __uint_as_float(__builtin_amdgcn_readlane(__float_as_uint(v), lane));
}

__global__ __launch_bounds__(MLP_BLOCK) void mlp_kernel(
    const float* __restrict__ verts,
    const float* __restrict__ grid_verts,
    const float* __restrict__ grid_feat,
    const float* __restrict__ pre,
    const float* __restrict__ aux,
    const float* __restrict__ cst,
    const int*   __restrict__ knn_idx,
    const float* __restrict__ ew1,
    const float* __restrict__ eg1, const float* __restrict__ ebt1,
    const float* __restrict__ ew2, const float* __restrict__ eb2,
    const float* __restrict__ ow1, const float* __restrict__ ob1,
    const float* __restrict__ og1, const float* __restrict__ obt1,
    const float* __restrict__ ow2, const float* __restrict__ ob2,
    float* __restrict__ out)
{
    __shared__ float s_ew1r[3 * 64];
    __shared__ float s_ew2[64 * 64];
    __shared__ float s_ow1[160 * 64];
    __shared__ float s_ow2[64 * 64];
    __shared__ float s_eg1[64], s_ebt1[64], s_eb2[64];
    __shared__ float s_ob1[64], s_og1[64], s_obt1[64], s_ob2[64];

    const int tid = threadIdx.x;
    for (int t = tid; t < 3 * 64;  t += MLP_BLOCK) s_ew1r[t] = ew1[32 * 64 + t];
    for (int t = tid; t < 64 * 64; t += MLP_BLOCK) s_ew2[t]  = ew2[t];
    for (int t = tid; t < 160 * 64; t += MLP_BLOCK) s_ow1[t] = ow1[t];
    for (int t = tid; t < 64 * 64; t += MLP_BLOCK) s_ow2[t]  = ow2[t];
    if (tid < 64) {
        s_eg1[tid] = eg1[tid];  s_ebt1[tid] = ebt1[tid]; s_eb2[tid] = eb2[tid];
        s_ob1[tid] = ob1[tid];  s_og1[tid] = og1[tid];
        s_obt1[tid] = obt1[tid]; s_ob2[tid] = ob2[tid];
    }
    __syncthreads();

    const int lane = tid & 63;
    const int wave = tid >> 6;
    const int c    = lane;
    const int grp  = blockIdx.x * WPB + wave;
    const int m0   = __builtin_amdgcn_readfirstlane(grp * MT);

    const float Ws0 = cst[0], Ws1 = cst[1], Ws2 = cst[2];
    const float Gxx = cst[3], Gyy = cst[4], Gzz = cst[5];
    const float Gxy = cst[6], Gxz = cst[7], Gyz = cst[8];

    float gvx[MT], gvy[MT], gvz[MT];
#pragma unroll
    for (int p = 0; p < MT; ++p) {
        gvx[p] = grid_verts[(m0 + p) * 3 + 0];
        gvy[p] = grid_verts[(m0 + p) * 3 + 1];
        gvz[p] = grid_verts[(m0 + p) * 3 + 2];
    }

    float gsum[MT];
#pragma unroll
    for (int p = 0; p < MT; ++p) gsum[p] = 0.0f;

    const float inv64 = 1.0f / 64.0f;
    for (int p = 0; p < MT; ++p) {
        for (int j = 0; j < KNN; ++j) {
            int n = __builtin_amdgcn_readfirstlane(knn_idx[(m0 + p) * KNN + j]);
            float S1  = aux[n * 8 + 0], Q = aux[n * 8 + 1];
            float P1x = aux[n * 8 + 2], P1y = aux[n * 8 + 3], P1z = aux[n * 8 + 4];
            float rx = verts[n * 3 + 0] - gvx[p];
            float ry = verts[n * 3 + 1] - gvy[p];
            float rz = verts[n * 3 + 2] - gvz[p];
            float hv = pre[(size_t)n * COUT + c];
            hv = fmaf(rx, s_ew1r[0 * 64 + c], hv);
            hv = fmaf(ry, s_ew1r[1 * 64 + c], hv);
            hv = fmaf(rz, s_ew1r[2 * 64 + c], hv);
            float s1 = S1 + rx * Ws0 + ry * Ws1 + rz * Ws2;
            float s2 = Q + 2.0f * (rx * P1x + ry * P1y + rz * P1z)
                     + rx * rx * Gxx + ry * ry * Gyy + rz * rz * Gzz
                     + 2.0f * (rx * ry * Gxy + rx * rz * Gxz + ry * rz * Gyz);
            float mean = s1 * inv64;
            float var  = s2 * inv64 - mean * mean;
            float xn = (hv - mean) * rsqrtf(var + 1e-5f);
            gsum[p] += gelu_fast(xn * s_eg1[c] + s_ebt1[c]);
        }
    }

    float A[MT];
#pragma unroll
    for (int p = 0; p < MT; ++p) { gsum[p] *= (1.0f / 16.0f); A[p] = s_eb2[c]; }
    for (int jj = 0; jj < 64; ++jj) {
        float w = s_ew2[jj * 64 + c];
#pragma unroll
        for (int p = 0; p < MT; ++p)
            A[p] = fmaf(lane_bcast(gsum[p], jj), w, A[p]);
    }

    float gfa[MT], gfb[MT];
#pragma unroll
    for (int p = 0; p < MT; ++p) {
        gfa[p] = grid_feat[(size_t)(m0 + p) * CPROV + c];
        gfb[p] = grid_feat[(size_t)(m0 + p) * CPROV + 64 + (c & 31)];
    }
    float t1[MT];
#pragma unroll
    for (int p = 0; p < MT; ++p) t1[p] = s_ob1[c];
    for (int jj = 0; jj < 64; ++jj) {
        float w = s_ow1[jj * 64 + c];
#pragma unroll
        for (int p = 0; p < MT; ++p)
            t1[p] = fmaf(lane_bcast(A[p], jj), w, t1[p]);
    }
    for (int i = 0; i < 64; ++i) {
        float w = s_ow1[(64 + i) * 64 + c];
#pragma unroll
        for (int p = 0; p < MT; ++p)
            t1[p] = fmaf(lane_bcast(gfa[p], i), w, t1[p]);
    }
    for (int i = 0; i < 32; ++i) {
        float w = s_ow1[(128 + i) * 64 + c];
#pragma unroll
        for (int p = 0; p < MT; ++p)
            t1[p] = fmaf(lane_bcast(gfb[p], i), w, t1[p]);
    }

#pragma unroll
    for (int p = 0; p < MT; ++p) {
        float x = t1[p];
        float s = x, s2 = x * x;
#pragma unroll
        for (int off = 32; off; off >>= 1) {
            s  += __shfl_xor(s, off);
            s2 += __shfl_xor(s2, off);
        }
        float mean = s * inv64;
        float var  = s2 * inv64 - mean * mean;
        float xn = (x - mean) * rsqrtf(var + 1e-5f);
        t1[p] = gelu_fast(xn * s_og1[c] + s_obt1[c]);
    }

    float o[MT];
#pragma unroll
    for (int p = 0; p < MT; ++p) o[p] = s_ob2[c];
    for (int jj = 0; jj < 64; ++jj) {
        float w = s_ow2[jj * 64 + c];
#pragma unroll
        for (int p = 0; p < MT; ++p)
            o[p] = fmaf(lane_bcast(t1[p], jj), w, o[p]);
    }
#pragma unroll
    for (int p = 0; p < MT; ++p)
        out[(size_t)(m0 + p) * COUT + c] = o[p];
}

// ---------------------------------------------------------------------------
extern "C" void kernel_launch(void* const* d_in, const int* in_sizes, int n_in,
                              void* d_out, int out_size, void* d_ws, size_t ws_size,
                              hipStream_t stream)
{
    const float* verts  = (const float*)d_in[0];
    const float* feats  = (const float*)d_in[1];
    const float* gverts = (const float*)d_in[2];
    const float* gfeat  = (const float*)d_in[3];
    const float* ew1    = (const float*)d_in[4];
    const float* eb1    = (const float*)d_in[5];
    const float* eg1    = (const float*)d_in[6];
    const float* ebt1   = (const float*)d_in[7];
    const float* ew2    = (const float*)d_in[8];
    const float* eb2    = (const float*)d_in[9];
    const float* ow1    = (const float*)d_in[10];
    const float* ob1    = (const float*)d_in[11];
    const float* og1    = (const float*)d_in[12];
    const float* obt1   = (const float*)d_in[13];
    const float* ow2    = (const float*)d_in[14];
    const float* ob2    = (const float*)d_in[15];
    float* out = (float*)d_out;

    char* ws = (char*)d_ws;
    int*    counts  = (int*)(ws + 0);              // 128 KB
    int*    prefix  = (int*)(ws + 131072);         // 32769 ints
    float*  tau     = (float*)(ws + 262152);       // 128 KB
    int*    knn_idx = (int*)(ws + 393224);         // 2 MB -> ends 2490376
    unsigned long long* cand = (unsigned long long*)(ws + 2490376); // 16.78 MB
    // pre/aux/cst overlay cand (dead after knn_merge)
    float*  pre     = (float*)(ws + 2490376);      // 2 MB
    float*  aux     = (float*)(ws + 4587528);      // 256 KB
    float*  cst     = (float*)(ws + 4849672);      // 64 B

    hipMemsetAsync(counts, 0, 32768 * sizeof(int), stream);
    bin_count_kernel<<<NV / 256, 256, 0, stream>>>(verts, counts);
    prefix_kernel<<<1, 1024, 0, stream>>>(counts, prefix);
    radius_kernel<<<NM / 256, 256, 0, stream>>>(gverts, prefix, tau);
    knn_partial_kernel<<<dim3(NM / 256, NCH), 256, 0, stream>>>(verts, gverts, tau, cand);
    knn_merge_kernel<<<NM / 256, 256, 0, stream>>>(cand, knn_idx);
    pre_edge_kernel<<<(NV * COUT) / 256, 256, 0, stream>>>(feats, ew1, eb1, pre, aux);
    const_kernel<<<1, 64, 0, stream>>>(ew1, cst);
    mlp_kernel<<<NM / (MT * WPB), MLP_BLOCK, 0, stream>>>(verts, gverts, gfeat,
        pre, aux, cst, knn_idx,
        ew1, eg1, ebt1, ew2, eb2, ow1, ob1, og1, obt1, ow2, ob2, out);
}

// Round 9
// 402.056 us; speedup vs baseline: 2.5474x; 1.2301x over previous
//
#include <hip/hip_runtime.h>
#include <cfloat>
#include <cstdint>

#define NV    8192
#define NM    32768
#define KNN   16
#define CIN   32
#define COUT  64
#define CPROV 96
#define NCH   4
#define CHUNK 2048   // NV / NCH
#define SUB   256
#define NSUB  (CHUNK / SUB)
#define CAP   12
#define MT    8      // grid points per wave in mlp kernel
#define MLP_BLOCK 1024
#define WPB   (MLP_BLOCK/64)

// ===========================================================================
// KNN: R8's validated structure (full scan, index order, u64-key min-16,
// tau-seeded self-tightening gate, LDS FIFO + branchless merge), with the
// hot loop restructured for ILP:
//   - candidates processed 8 at a time (8 independent ds_read_b128 + 8
//     independent d2 chains)
//   - gate in d2-domain (1 float cmp); key build only for passers
//   - d2 = fmaf(-2,dot,qq+rr): bit-identical to (qq+rr)-2*dot since 2*dot
//     is exact (pow2 scale) => single rounding of the same real value.
// Golden d2 path (validated R4/R6/R8): q=grid*32, r=vert*32; qq/rr plain
// ascending mul/add; dot = fma(q2,r2, fma(q1,r1, q0*r0)).
// ===========================================================================

__device__ __forceinline__ unsigned long long d2key(float d2, unsigned int idx) {
    unsigned int b = __float_as_uint(d2);
    b ^= (b & 0x80000000u) ? 0xFFFFFFFFu : 0x80000000u;  // total-order map
    return ((unsigned long long)b << 32) | idx;
}

__device__ __forceinline__ float key_d2f(unsigned long long key) {
    unsigned int b = (unsigned int)(key >> 32);
    b = (b & 0x80000000u) ? (b ^ 0x80000000u) : ~b;      // inverse map
    return __uint_as_float(b);
}

__device__ __forceinline__ void key_insert(unsigned long long* a,
                                           unsigned long long key) {
    // branchless sorted (ascending) insert-and-drop-max
#pragma unroll
    for (int i = KNN - 1; i >= 1; --i) {
        unsigned long long hi = (a[i-1] > key) ? a[i-1] : key;
        a[i] = (hi < a[i]) ? hi : a[i];
    }
    a[0] = (key < a[0]) ? key : a[0];
}

__device__ __forceinline__ int bin_of(float x) {
    int b = (int)(x * 32.0f);
    return min(31, max(0, b));
}

__global__ __launch_bounds__(256) void bin_count_kernel(
    const float* __restrict__ verts, int* __restrict__ counts)
{
    int v = blockIdx.x * 256 + threadIdx.x;
    int bx = bin_of(verts[v * 3 + 0]);
    int by = bin_of(verts[v * 3 + 1]);
    int bz = bin_of(verts[v * 3 + 2]);
    atomicAdd(&counts[(bx * 32 + by) * 32 + bz], 1);
}

__global__ __launch_bounds__(1024) void prefix_kernel(
    const int* __restrict__ counts, int* __restrict__ prefix)
{
    __shared__ int lds[1024];
    int tid = threadIdx.x;
    int local[32]; int s = 0;
#pragma unroll
    for (int i = 0; i < 32; ++i) { local[i] = counts[tid * 32 + i]; s += local[i]; }
    lds[tid] = s; __syncthreads();
    for (int off = 1; off < 1024; off <<= 1) {
        int v = (tid >= off) ? lds[tid - off] : 0;
        __syncthreads();
        lds[tid] += v;
        __syncthreads();
    }
    int run = lds[tid] - s;
#pragma unroll
    for (int i = 0; i < 32; ++i) { prefix[tid * 32 + i] = run; run += local[i]; }
    if (tid == 1023) prefix[32768] = run;
}

// tau[m] = 3*(R+1)^2 where radius-R cell cube holds >= 16 points (validated R6/R8)
__global__ __launch_bounds__(256) void radius_kernel(
    const float* __restrict__ grid_verts, const int* __restrict__ prefix,
    float* __restrict__ tau)
{
    int m = blockIdx.x * 256 + threadIdx.x;
    int bx = bin_of(grid_verts[m * 3 + 0]);
    int by = bin_of(grid_verts[m * 3 + 1]);
    int bz = bin_of(grid_verts[m * 3 + 2]);
    int R = 1;
    for (; R < 32; ++R) {
        int cnt = 0;
        int xlo = max(0, bx - R), xhi = min(31, bx + R);
        int ylo = max(0, by - R), yhi = min(31, by + R);
        int zlo = max(0, bz - R), zhi = min(31, bz + R);
        for (int x = xlo; x <= xhi; ++x)
            for (int y = ylo; y <= yhi; ++y) {
                int c = (x * 32 + y) * 32;
                cnt += prefix[c + zhi + 1] - prefix[c + zlo];
            }
        if (cnt >= KNN) break;
    }
    float Rp = (float)(R + 1);
    tau[m] = 3.0f * Rp * Rp;
}

__global__ __launch_bounds__(256, 2) void knn_partial_kernel(
    const float* __restrict__ verts,
    const float* __restrict__ grid_verts,
    const float* __restrict__ tau,
    unsigned long long* __restrict__ cand)   // (NM, NCH*KNN)
{
    __shared__ float4 sv[SUB];                       // 4 KB
    __shared__ unsigned long long sbuf[CAP][256];    // 24 KB
    const int tid   = threadIdx.x;
    const int m     = blockIdx.x * 256 + tid;
    const int chunk = blockIdx.y;

    const float q0 = __fmul_rn(grid_verts[m * 3 + 0], 32.0f);
    const float q1 = __fmul_rn(grid_verts[m * 3 + 1], 32.0f);
    const float q2 = __fmul_rn(grid_verts[m * 3 + 2], 32.0f);
    const float qq = __fadd_rn(__fadd_rn(__fmul_rn(q0, q0), __fmul_rn(q1, q1)),
                               __fmul_rn(q2, q2));

    // seed = key(bound), idx 0; bound > all golden top-16 d2 (validated margin)
    const float bound = tau[m] + 0.13f;
    unsigned int bb = __float_as_uint(bound) ^ 0x80000000u;  // bound > 0
    const unsigned long long seed = ((unsigned long long)bb << 32);

    unsigned long long a[KNN];
#pragma unroll
    for (int s = 0; s < KNN; ++s) a[s] = seed;
    float gd = bound;      // d2-domain gate = d2 part of a[15]
    int cnt = 0;

    for (int sub = 0; sub < NSUB; ++sub) {
        __syncthreads();
        {
            int v = chunk * CHUNK + sub * SUB + tid;
            float r0 = __fmul_rn(verts[v * 3 + 0], 32.0f);
            float r1 = __fmul_rn(verts[v * 3 + 1], 32.0f);
            float r2 = __fmul_rn(verts[v * 3 + 2], 32.0f);
            float rr = __fadd_rn(__fadd_rn(__fmul_rn(r0, r0), __fmul_rn(r1, r1)),
                                 __fmul_rn(r2, r2));
            sv[tid] = make_float4(r0, r1, r2, rr);
        }
        __syncthreads();

        const unsigned int base = chunk * CHUNK + sub * SUB;
        for (int t = 0; t < SUB; t += 8) {
            float d2v[8];
#pragma unroll
            for (int k = 0; k < 8; ++k) {
                float4 v = sv[t + k];
                float dot = fmaf(q2, v.z, fmaf(q1, v.y, __fmul_rn(q0, v.x)));
                // == (qq+rr) - 2*dot bit-exactly (2*dot exact)
                d2v[k] = fmaf(-2.0f, dot, __fadd_rn(qq, v.w));
            }
#pragma unroll
            for (int k = 0; k < 8; ++k) {
                if (d2v[k] <= gd) {     // conservative: ties resolved by insert
                    unsigned long long key = d2key(d2v[k], base + t + k);
                    if (cnt < CAP) { sbuf[cnt][tid] = key; ++cnt; }
                    else {  // rare overflow: exact direct insert, tighten gate
                        key_insert(a, key);
                        gd = key_d2f(a[KNN - 1]);
                    }
                }
            }
        }
        // merge private FIFO (lane-private; no barrier needed)
        int mx = cnt;
#pragma unroll
        for (int off = 32; off; off >>= 1) mx = max(mx, __shfl_xor(mx, off));
        for (int k = 0; k < mx; ++k) {
            unsigned long long key = (k < cnt) ? sbuf[k][tid] : ~0ULL;
            key_insert(a, key);
        }
        if (mx) gd = key_d2f(a[KNN - 1]);
        cnt = 0;
    }

    unsigned long long* o = cand + (size_t)m * (NCH * KNN) + chunk * KNN;
#pragma unroll
    for (int s = 0; s < KNN; ++s) o[s] = a[s];
}

__global__ __launch_bounds__(256) void knn_merge_kernel(
    const unsigned long long* __restrict__ cand, int* __restrict__ knn_idx)
{
    const int m = blockIdx.x * 256 + threadIdx.x;
    unsigned long long a[KNN];
#pragma unroll
    for (int s = 0; s < KNN; ++s) a[s] = ~0ULL;
    for (int k = 0; k < NCH * KNN; ++k) {
        unsigned long long key = cand[(size_t)m * (NCH * KNN) + k];
        if (key < a[KNN - 1]) key_insert(a, key);
    }
#pragma unroll
    for (int s = 0; s < KNN; ++s)
        knn_idx[m * KNN + s] = (int)(a[s] & 0xFFFFFFFFu);
}

// ===========================================================================
// MLP precompute (unchanged from R6/R8 — passed)
// ===========================================================================

__global__ void const_kernel(const float* __restrict__ ew1, float* __restrict__ cst)
{
    int c = threadIdx.x;   // 64 threads
    float w0 = ew1[32 * 64 + c], w1 = ew1[33 * 64 + c], w2 = ew1[34 * 64 + c];
    float v[9] = { w0, w1, w2, w0*w0, w1*w1, w2*w2, w0*w1, w0*w2, w1*w2 };
#pragma unroll
    for (int k = 0; k < 9; ++k) {
#pragma unroll
        for (int off = 32; off; off >>= 1) v[k] += __shfl_xor(v[k], off);
    }
    if (c == 0) {
        cst[0] = v[0]; cst[1] = v[1]; cst[2] = v[2];
        cst[3] = v[3]; cst[4] = v[4]; cst[5] = v[5];
        cst[6] = v[6]; cst[7] = v[7]; cst[8] = v[8];
    }
}

__global__ __launch_bounds__(256) void pre_edge_kernel(
    const float* __restrict__ feats, const float* __restrict__ ew1,
    const float* __restrict__ eb1, float* __restrict__ pre,
    float* __restrict__ aux)
{
    int t = blockIdx.x * 256 + threadIdx.x;
    int n = t >> 6, c = t & 63;
    float acc = eb1[c];
#pragma unroll
    for (int i = 0; i < CIN; ++i)
        acc = fmaf(feats[n * CIN + i], ew1[i * COUT + c], acc);
    pre[t] = acc;

    float w0 = ew1[32 * 64 + c], w1 = ew1[33 * 64 + c], w2 = ew1[34 * 64 + c];
    float v[5] = { acc, acc * acc, acc * w0, acc * w1, acc * w2 };
#pragma unroll
    for (int k = 0; k < 5; ++k) {
#pragma unroll
        for (int off = 32; off; off >>= 1) v[k] += __shfl_xor(v[k], off);
    }
    if (c == 0) {
        aux[n * 8 + 0] = v[0]; aux[n * 8 + 1] = v[1];
        aux[n * 8 + 2] = v[2]; aux[n * 8 + 3] = v[3]; aux[n * 8 + 4] = v[4];
    }
}

// ===========================================================================
// Main MLP (unchanged from R6/R8 — passed)
// ===========================================================================
__device__ __forceinline__ float gelu_fast(float x) {
    float t = fmaf(0.044715f, x * x, 1.0f);
    float u = 0.7978845608028654f * x * t;
    float e = __expf(-2.0f * u);
    return x * __builtin_amdgcn_rcpf(1.0f + e);
}

__device__ __forceinline__ float lane_bcast(float v, int lane) {
    return __uint_as_float(__builtin_amdgcn_readlane(__float_as_uint(v), lane));
}

__global__ __launch_bounds__(MLP_BLOCK) void mlp_kernel(
    const float* __restrict__ verts,
    const float* __restrict__ grid_verts,
    const float* __restrict__ grid_feat,
    const float* __restrict__ pre,
    const float* __restrict__ aux,
    const float* __restrict__ cst,
    const int*   __restrict__ knn_idx,
    const float* __restrict__ ew1,
    const float* __restrict__ eg1, const float* __restrict__ ebt1,
    const float* __restrict__ ew2, const float* __restrict__ eb2,
    const float* __restrict__ ow1, const float* __restrict__ ob1,
    const float* __restrict__ og1, const float* __restrict__ obt1,
    const float* __restrict__ ow2, const float* __restrict__ ob2,
    float* __restrict__ out)
{
    __shared__ float s_ew1r[3 * 64];
    __shared__ float s_ew2[64 * 64];
    __shared__ float s_ow1[160 * 64];
    __shared__ float s_ow2[64 * 64];
    __shared__ float s_eg1[64], s_ebt1[64], s_eb2[64];
    __shared__ float s_ob1[64], s_og1[64], s_obt1[64], s_ob2[64];

    const int tid = threadIdx.x;
    for (int t = tid; t < 3 * 64;  t += MLP_BLOCK) s_ew1r[t] = ew1[32 * 64 + t];
    for (int t = tid; t < 64 * 64; t += MLP_BLOCK) s_ew2[t]  = ew2[t];
    for (int t = tid; t < 160 * 64; t += MLP_BLOCK) s_ow1[t] = ow1[t];
    for (int t = tid; t < 64 * 64; t += MLP_BLOCK) s_ow2[t]  = ow2[t];
    if (tid < 64) {
        s_eg1[tid] = eg1[tid];  s_ebt1[tid] = ebt1[tid]; s_eb2[tid] = eb2[tid];
        s_ob1[tid] = ob1[tid];  s_og1[tid] = og1[tid];
        s_obt1[tid] = obt1[tid]; s_ob2[tid] = ob2[tid];
    }
    __syncthreads();

    const int lane = tid & 63;
    const int wave = tid >> 6;
    const int c    = lane;
    const int grp  = blockIdx.x * WPB + wave;
    const int m0   = __builtin_amdgcn_readfirstlane(grp * MT);

    const float Ws0 = cst[0], Ws1 = cst[1], Ws2 = cst[2];
    const float Gxx = cst[3], Gyy = cst[4], Gzz = cst[5];
    const float Gxy = cst[6], Gxz = cst[7], Gyz = cst[8];

    float gvx[MT], gvy[MT], gvz[MT];
#pragma unroll
    for (int p = 0; p < MT; ++p) {
        gvx[p] = grid_verts[(m0 + p) * 3 + 0];
        gvy[p] = grid_verts[(m0 + p) * 3 + 1];
        gvz[p] = grid_verts[(m0 + p) * 3 + 2];
    }

    float gsum[MT];
#pragma unroll
    for (int p = 0; p < MT; ++p) gsum[p] = 0.0f;

    const float inv64 = 1.0f / 64.0f;
    for (int p = 0; p < MT; ++p) {
        for (int j = 0; j < KNN; ++j) {
            int n = __builtin_amdgcn_readfirstlane(knn_idx[(m0 + p) * KNN + j]);
            float S1  = aux[n * 8 + 0], Q = aux[n * 8 + 1];
            float P1x = aux[n * 8 + 2], P1y = aux[n * 8 + 3], P1z = aux[n * 8 + 4];
            float rx = verts[n * 3 + 0] - gvx[p];
            float ry = verts[n * 3 + 1] - gvy[p];
            float rz = verts[n * 3 + 2] - gvz[p];
            float hv = pre[(size_t)n * COUT + c];
            hv = fmaf(rx, s_ew1r[0 * 64 + c], hv);
            hv = fmaf(ry, s_ew1r[1 * 64 + c], hv);
            hv = fmaf(rz, s_ew1r[2 * 64 + c], hv);
            float s1 = S1 + rx * Ws0 + ry * Ws1 + rz * Ws2;
            float s2 = Q + 2.0f * (rx * P1x + ry * P1y + rz * P1z)
                     + rx * rx * Gxx + ry * ry * Gyy + rz * rz * Gzz
                     + 2.0f * (rx * ry * Gxy + rx * rz * Gxz + ry * rz * Gyz);
            float mean = s1 * inv64;
            float var  = s2 * inv64 - mean * mean;
            float xn = (hv - mean) * rsqrtf(var + 1e-5f);
            gsum[p] += gelu_fast(xn * s_eg1[c] + s_ebt1[c]);
        }
    }

    float A[MT];
#pragma unroll
    for (int p = 0; p < MT; ++p) { gsum[p] *= (1.0f / 16.0f); A[p] = s_eb2[c]; }
    for (int jj = 0; jj < 64; ++jj) {
        float w = s_ew2[jj * 64 + c];
#pragma unroll
        for (int p = 0; p < MT; ++p)
            A[p] = fmaf(lane_bcast(gsum[p], jj), w, A[p]);
    }

    float gfa[MT], gfb[MT];
#pragma unroll
    for (int p = 0; p < MT; ++p) {
        gfa[p] = grid_feat[(size_t)(m0 + p) * CPROV + c];
        gfb[p] = grid_feat[(size_t)(m0 + p) * CPROV + 64 + (c & 31)];
    }
    float t1[MT];
#pragma unroll
    for (int p = 0; p < MT; ++p) t1[p] = s_ob1[c];
    for (int jj = 0; jj < 64; ++jj) {
        float w = s_ow1[jj * 64 + c];
#pragma unroll
        for (int p = 0; p < MT; ++p)
            t1[p] = fmaf(lane_bcast(A[p], jj), w, t1[p]);
    }
    for (int i = 0; i < 64; ++i) {
        float w = s_ow1[(64 + i) * 64 + c];
#pragma unroll
        for (int p = 0; p < MT; ++p)
            t1[p] = fmaf(lane_bcast(gfa[p], i), w, t1[p]);
    }
    for (int i = 0; i < 32; ++i) {
        float w = s_ow1[(128 + i) * 64 + c];
#pragma unroll
        for (int p = 0; p < MT; ++p)
            t1[p] = fmaf(lane_bcast(gfb[p], i), w, t1[p]);
    }

#pragma unroll
    for (int p = 0; p < MT; ++p) {
        float x = t1[p];
        float s = x, s2 = x * x;
#pragma unroll
        for (int off = 32; off; off >>= 1) {
            s  += __shfl_xor(s, off);
            s2 += __shfl_xor(s2, off);
        }
        float mean = s * inv64;
        float var  = s2 * inv64 - mean * mean;
        float xn = (x - mean) * rsqrtf(var + 1e-5f);
        t1[p] = gelu_fast(xn * s_og1[c] + s_obt1[c]);
    }

    float o[MT];
#pragma unroll
    for (int p = 0; p < MT; ++p) o[p] = s_ob2[c];
    for (int jj = 0; jj < 64; ++jj) {
        float w = s_ow2[jj * 64 + c];
#pragma unroll
        for (int p = 0; p < MT; ++p)
            o[p] = fmaf(lane_bcast(t1[p], jj), w, o[p]);
    }
#pragma unroll
    for (int p = 0; p < MT; ++p)
        out[(size_t)(m0 + p) * COUT + c] = o[p];
}

// ---------------------------------------------------------------------------
extern "C" void kernel_launch(void* const* d_in, const int* in_sizes, int n_in,
                              void* d_out, int out_size, void* d_ws, size_t ws_size,
                              hipStream_t stream)
{
    const float* verts  = (const float*)d_in[0];
    const float* feats  = (const float*)d_in[1];
    const float* gverts = (const float*)d_in[2];
    const float* gfeat  = (const float*)d_in[3];
    const float* ew1    = (const float*)d_in[4];
    const float* eb1    = (const float*)d_in[5];
    const float* eg1    = (const float*)d_in[6];
    const float* ebt1   = (const float*)d_in[7];
    const float* ew2    = (const float*)d_in[8];
    const float* eb2    = (const float*)d_in[9];
    const float* ow1    = (const float*)d_in[10];
    const float* ob1    = (const float*)d_in[11];
    const float* og1    = (const float*)d_in[12];
    const float* obt1   = (const float*)d_in[13];
    const float* ow2    = (const float*)d_in[14];
    const float* ob2    = (const float*)d_in[15];
    float* out = (float*)d_out;

    char* ws = (char*)d_ws;
    int*    counts  = (int*)(ws + 0);              // 128 KB
    int*    prefix  = (int*)(ws + 131072);         // 32769 ints
    float*  tau     = (float*)(ws + 262152);       // 128 KB
    int*    knn_idx = (int*)(ws + 393224);         // 2 MB -> ends 2490376
    unsigned long long* cand = (unsigned long long*)(ws + 2490376); // 16.78 MB
    // pre/aux/cst overlay cand (dead after knn_merge)
    float*  pre     = (float*)(ws + 2490376);      // 2 MB
    float*  aux     = (float*)(ws + 4587528);      // 256 KB
    float*  cst     = (float*)(ws + 4849672);      // 64 B

    hipMemsetAsync(counts, 0, 32768 * sizeof(int), stream);
    bin_count_kernel<<<NV / 256, 256, 0, stream>>>(verts, counts);
    prefix_kernel<<<1, 1024, 0, stream>>>(counts, prefix);
    radius_kernel<<<NM / 256, 256, 0, stream>>>(gverts, prefix, tau);
    knn_partial_kernel<<<dim3(NM / 256, NCH), 256, 0, stream>>>(verts, gverts, tau, cand);
    knn_merge_kernel<<<NM / 256, 256, 0, stream>>>(cand, knn_idx);
    pre_edge_kernel<<<(NV * COUT) / 256, 256, 0, stream>>>(feats, ew1, eb1, pre, aux);
    const_kernel<<<1, 64, 0, stream>>>(ew1, cst);
    mlp_kernel<<<NM / (MT * WPB), MLP_BLOCK, 0, stream>>>(verts, gverts, gfeat,
        pre, aux, cst, knn_idx,
        ew1, eg1, ebt1, ew2, eb2, ow1, ob1, og1, obt1, ow2, ob2, out);
}